// Round 6
// baseline (247.618 us; speedup 1.0000x reference)
//
#include <hip/hip_runtime.h>
#include <hip/hip_bf16.h>

// B=4, C=128, H=W=64 -> N=4096. ALL I/O FP32.
// Round 6: proj outputs staged through LDS -> contiguous dwordx4 stores
// (was 96 scalar b16 stores/thread). Flash: 3 blocks/CU (launch_bounds),
// P-scratch pitch 66 (conflict-free reads). Combine on 512 blocks.

#define BATCH 4
#define CH    128
#define NTOK  4096
#define TK    64
#define SCALE 0.08838834764831845f   // 1/sqrt(128)
#define LOG2E 1.4426950408889634f
#define MFIX  16.0f                  // fixed softmax offset (log2 units)
#define PSTR  66                     // P scratch row stride (ushort): 132 B = 33 banks

typedef __attribute__((ext_vector_type(8)))  short short8;
typedef __attribute__((ext_vector_type(4)))  float f32x4;
typedef __attribute__((ext_vector_type(16))) float f32x16;

static __device__ __forceinline__ unsigned short f2bf(float f) {
    __hip_bfloat16 h = (__hip_bfloat16)f;
    return *(const unsigned short*)&h;
}

// ---------------- W fp32 -> bf16 ----------------
__global__ __launch_bounds__(256) void convert_w_kernel(
    const float* __restrict__ Wq, const float* __restrict__ Wk,
    const float* __restrict__ Wv, unsigned short* __restrict__ wb)
{
    const int idx = (blockIdx.x * 256 + threadIdx.x) * 4;
    const float* srcs[3] = {Wq, Wk, Wv};
    #pragma unroll
    for (int m = 0; m < 3; ++m) {
        float4 v = *(const float4*)(srcs[m] + idx);
        unsigned short o[4] = {f2bf(v.x), f2bf(v.y), f2bf(v.z), f2bf(v.w)};
        *(uint2*)(wb + (size_t)m * CH * CH + idx) = *(const uint2*)o;
    }
}

// ---------------- MFMA QKV projection ----------------
// grid (NTOK/64, BATCH), 256 thr. x tile staged transposed (XOR-swizzled) in
// XsT; Q/K/V results staged in StgA/StgB then stored as contiguous dwordx4.
__global__ __launch_bounds__(256) void proj_mfma_kernel(
    const float* __restrict__ x,
    const unsigned short* __restrict__ wqb, const unsigned short* __restrict__ wkb,
    const unsigned short* __restrict__ wvb,
    const float* __restrict__ bq, const float* __restrict__ bk,
    const float* __restrict__ bv,
    unsigned short* __restrict__ q_ws, unsigned short* __restrict__ k_ws,
    unsigned short* __restrict__ vt_ws)
{
    __shared__ __align__(16) unsigned short XsT[64 * CH];   // 16 KB, swizzled
    __shared__ __align__(16) unsigned short StgA[8448];     // 64x130 (QK) / 128x66 (V)
    __shared__ __align__(16) unsigned short StgB[8448];     // 64x130 (K)

    const int t    = threadIdx.x;
    const int w    = t >> 6;
    const int lane = t & 63;
    const int quad = lane >> 4;
    const int c16  = lane & 15;
    const int n0   = blockIdx.x * 64;
    const int b    = blockIdx.y;
    const float* xb = x + (size_t)b * CH * NTOK;

    // --- stage x^T: wave w covers channels 32w..32w+31; lane = token ---
    {
        const int tok = lane;
        #pragma unroll
        for (int cc = 0; cc < 4; ++cc) {
            const int cb = 32 * w + 8 * cc;
            unsigned short tmp[8];
            #pragma unroll
            for (int j = 0; j < 8; ++j)
                tmp[j] = f2bf(xb[(size_t)(cb + j) * NTOK + n0 + tok]);
            const int phys = ((cb >> 3) ^ (tok & 15));
            *(short8*)&XsT[tok * CH + phys * 8] = *(const short8*)tmp;
        }
    }
    __syncthreads();

    // x A-frags (M = tokens 16w..16w+15): A[m=c16][k=32ks+8quad+j]
    short8 xa[4];
    #pragma unroll
    for (int ks = 0; ks < 4; ++ks)
        xa[ks] = *(const short8*)&XsT[(16 * w + c16) * CH + (((4 * ks + quad) ^ c16) << 3)];

    // ---- Q/K -> LDS stages (row = token, pitch 130) ----
    #pragma unroll
    for (int nt = 0; nt < 8; ++nt) {
        f32x4 aq = (f32x4){0.f, 0.f, 0.f, 0.f};
        f32x4 ak = (f32x4){0.f, 0.f, 0.f, 0.f};
        const unsigned short* wqr = wqb + (16 * nt + c16) * CH;
        const unsigned short* wkr = wkb + (16 * nt + c16) * CH;
        #pragma unroll
        for (int ks = 0; ks < 4; ++ks) {
            const short8 bqf = *(const short8*)(wqr + 32 * ks + 8 * quad);
            const short8 bkf = *(const short8*)(wkr + 32 * ks + 8 * quad);
            aq = __builtin_amdgcn_mfma_f32_16x16x32_bf16(xa[ks], bqf, aq, 0, 0, 0);
            ak = __builtin_amdgcn_mfma_f32_16x16x32_bf16(xa[ks], bkf, ak, 0, 0, 0);
        }
        const float bqv = bq[16 * nt + c16];
        const float bkv = bk[16 * nt + c16];
        #pragma unroll
        for (int r = 0; r < 4; ++r) {
            const int row = 16 * w + 4 * quad + r;          // token within tile
            StgA[row * 130 + 16 * nt + c16] = f2bf((aq[r] + bqv) * (SCALE * LOG2E));
            StgB[row * 130 + 16 * nt + c16] = f2bf(ak[r] + bkv);
        }
    }
    __syncthreads();

    // --- coalesced store Q,K: [n][c], 256 B contiguous per 4 threads ---
    {
        const int row = t >> 2, seg = t & 3;
        unsigned short* qdst = q_ws + ((size_t)b * NTOK + n0 + row) * CH + seg * 32;
        unsigned short* kdst = k_ws + ((size_t)b * NTOK + n0 + row) * CH + seg * 32;
        #pragma unroll
        for (int k = 0; k < 4; ++k) {
            *(short8*)(qdst + k * 8) = *(const short8*)&StgA[row * 130 + seg * 32 + k * 8];
            *(short8*)(kdst + k * 8) = *(const short8*)&StgB[row * 130 + seg * 32 + k * 8];
        }
    }
    __syncthreads();   // StgA reused for V below

    // ---- V (transposed output) -> StgA as [128 ch][66 pitch] ----
    #pragma unroll
    for (int mt = 0; mt < 2; ++mt) {
        short8 wva[4];
        const int crow16 = 16 * (2 * w + mt);
        #pragma unroll
        for (int ks = 0; ks < 4; ++ks)
            wva[ks] = *(const short8*)&wvb[(crow16 + c16) * CH + 32 * ks + 8 * quad];
        #pragma unroll
        for (int nt = 0; nt < 4; ++nt) {
            short8 xbf[4];
            #pragma unroll
            for (int ks = 0; ks < 4; ++ks)
                xbf[ks] = *(const short8*)&XsT[(16 * nt + c16) * CH + (((4 * ks + quad) ^ c16) << 3)];
            f32x4 acc = (f32x4){0.f, 0.f, 0.f, 0.f};
            #pragma unroll
            for (int ks = 0; ks < 4; ++ks)
                acc = __builtin_amdgcn_mfma_f32_16x16x32_bf16(wva[ks], xbf[ks], acc, 0, 0, 0);
            #pragma unroll
            for (int r = 0; r < 4; ++r) {
                const int crow = crow16 + 4 * quad + r;
                StgA[crow * 66 + 16 * nt + c16] = f2bf(acc[r] + bv[crow]);
            }
        }
    }
    __syncthreads();

    // --- coalesced store V^T: [c][n], 128 B contiguous per 2 threads ---
    {
        const int c = t >> 1, th = t & 1;
        unsigned short* vdst = vt_ws + ((size_t)b * CH + c) * NTOK + n0 + th * 32;
        #pragma unroll
        for (int k = 0; k < 4; ++k)
            *(short8*)(vdst + k * 8) = *(const short8*)&StgA[c * 66 + th * 32 + k * 8];
    }
}

// ---------------- split-KV MFMA flash attention (fixed-m, 32x32 tiles) ------
// block = 256 thr = 4 waves x 32 Q-rows = 128 rows. grid (32, SPLIT, B).
template <int SPLIT>
__global__ __launch_bounds__(256, 3) void flash_attn_mfma(
    const unsigned short* __restrict__ q_ws,
    const unsigned short* __restrict__ k_ws,
    const unsigned short* __restrict__ vt_ws,
    float* __restrict__ out,
    float* __restrict__ Op, float* __restrict__ l_p)
{
    __shared__ __align__(16) unsigned short KsU[TK * CH];        // 16 KB
    __shared__ __align__(16) unsigned short VtU[CH * TK];        // 16 KB
    __shared__ __align__(16) unsigned short PlU[4 * 32 * PSTR];  // 16.5 KB

    const int t    = threadIdx.x;
    const int w    = t >> 6;
    const int lane = t & 63;
    const int half = lane >> 5;
    const int l32  = lane & 31;
    const int jc   = blockIdx.y;
    const int b    = blockIdx.z;
    const int n0   = blockIdx.x * 128;
    const int jbeg = jc * (NTOK / SPLIT);
    const int jend = jbeg + (NTOK / SPLIT);

    // Q A-frags: wave rows n0+32w .. +31. A[m=l32][k=16ks+8half+j]
    short8 qa[8];
    {
        const unsigned short* qrow = q_ws + ((size_t)b * NTOK + n0 + 32 * w + l32) * CH;
        #pragma unroll
        for (int ks = 0; ks < 8; ++ks)
            qa[ks] = *(const short8*)(qrow + ks * 16 + half * 8);
    }

    f32x16 Oa[4];
    #pragma unroll
    for (int ct = 0; ct < 4; ++ct) Oa[ct] = (f32x16)(0.0f);
    f32x16 La = (f32x16)(0.0f);

    const unsigned short* kg = k_ws  + (size_t)b * NTOK * CH;
    const unsigned short* vg = vt_ws + (size_t)b * CH * NTOK;
    const short8 ones8 = (short8)(short)0x3F80;  // bf16 1.0 x8
    unsigned short* Pw = &PlU[w * 32 * PSTR];

    for (int j0 = jbeg; j0 < jend; j0 += TK) {
        __syncthreads();

        {   // stage K rows 16w..16w+15 (XOR-swizzled source, lane-contig dest)
            const int rl = lane >> 4, u = lane & 15;
            #pragma unroll
            for (int ci = 0; ci < 4; ++ci) {
                const int row = 16 * w + 4 * ci + rl;
                const int g   = u ^ (row & 15);
                const unsigned short* src = kg + (size_t)(j0 + row) * CH + g * 8;
                __builtin_amdgcn_global_load_lds(
                    (const __attribute__((address_space(1))) void*)src,
                    (__attribute__((address_space(3))) void*)&KsU[(16 * w + 4 * ci) * CH],
                    16, 0, 0);
            }
        }
        {   // stage V^T channel rows 32w..32w+31
            const int cl = lane >> 3, u = lane & 7;
            #pragma unroll
            for (int ci = 0; ci < 4; ++ci) {
                const int c = 32 * w + 8 * ci + cl;
                const int g = u ^ (c & 7);
                const unsigned short* src = vg + (size_t)c * NTOK + j0 + g * 8;
                __builtin_amdgcn_global_load_lds(
                    (const __attribute__((address_space(1))) void*)src,
                    (__attribute__((address_space(3))) void*)&VtU[(32 * w + 8 * ci) * TK],
                    16, 0, 0);
            }
        }
        __syncthreads();

        // --- S = Q K^T - MFIX : two 32x32 token tiles, 8 k-steps each ---
        f32x16 s0 = (f32x16)(-MFIX);
        f32x16 s1 = (f32x16)(-MFIX);
        #pragma unroll
        for (int ks = 0; ks < 8; ++ks) {
            const int ph = (2 * ks + half) ^ (l32 & 15);
            const short8 kf0 = *(const short8*)&KsU[l32 * CH + ph * 8];
            const short8 kf1 = *(const short8*)&KsU[(32 + l32) * CH + ph * 8];
            s0 = __builtin_amdgcn_mfma_f32_32x32x16_bf16(qa[ks], kf0, s0, 0, 0, 0);
            s1 = __builtin_amdgcn_mfma_f32_32x32x16_bf16(qa[ks], kf1, s1, 0, 0, 0);
        }

        // --- P = exp2(S) (m fixed) -> per-wave LDS scratch, row-major ---
        #pragma unroll
        for (int reg = 0; reg < 16; ++reg) {
            const int row = (reg & 3) + 8 * (reg >> 2) + 4 * half;
            Pw[row * PSTR + l32]      = f2bf(exp2f(s0[reg]));
            Pw[row * PSTR + 32 + l32] = f2bf(exp2f(s1[reg]));
        }
        __threadfence_block();

        // --- O += P V ; l += P * ones (no rescale: m is fixed) ---
        #pragma unroll
        for (int ks2 = 0; ks2 < 4; ++ks2) {
            const short8 pa = *(const short8*)&Pw[l32 * PSTR + ks2 * 16 + half * 8];
            #pragma unroll
            for (int ct = 0; ct < 4; ++ct) {
                const int ch = ct * 32 + l32;
                const int ph = (2 * ks2 + half) ^ (ch & 7);
                const short8 vf = *(const short8*)&VtU[ch * TK + ph * 8];
                Oa[ct] = __builtin_amdgcn_mfma_f32_32x32x16_bf16(pa, vf, Oa[ct], 0, 0, 0);
            }
            La = __builtin_amdgcn_mfma_f32_32x32x16_bf16(pa, ones8, La, 0, 0, 0);
        }
    }

    if constexpr (SPLIT == 1) {
        #pragma unroll
        for (int reg = 0; reg < 16; ++reg) {
            const int row = (reg & 3) + 8 * (reg >> 2) + 4 * half;
            const int n = n0 + 32 * w + row;
            const float inv = 1.0f / La[reg];
            #pragma unroll
            for (int ct = 0; ct < 4; ++ct)
                out[((size_t)b * CH + ct * 32 + l32) * NTOK + n] = Oa[ct][reg] * inv;
        }
    } else {
        const size_t chunk = (size_t)(b * SPLIT + jc);
        #pragma unroll
        for (int reg = 0; reg < 16; ++reg) {
            const int row = (reg & 3) + 8 * (reg >> 2) + 4 * half;
            const int n = n0 + 32 * w + row;
            const size_t base = (chunk * NTOK + n) * CH;
            #pragma unroll
            for (int ct = 0; ct < 4; ++ct)
                Op[base + ct * 32 + l32] = Oa[ct][reg];
            if (l32 == 0) l_p[chunk * NTOK + n] = La[reg];
        }
    }
}

// ---------------- combine partials (plain sums; fixed m) ----------------
template <int SPLIT>
__global__ __launch_bounds__(256) void combine_kernel(
    const float* __restrict__ Op, const float* __restrict__ l_p,
    float* __restrict__ out)
{
    const int t  = threadIdx.x;
    const int cg = t & 31;
    const int r8 = t >> 5;
    const int n0 = blockIdx.x * 32;
    const int b  = blockIdx.y;

    for (int it = 0; it < 4; ++it) {
        const int n = n0 + it * 8 + r8;
        float den = 0.f;
        float4 acc = make_float4(0.f, 0.f, 0.f, 0.f);
        #pragma unroll
        for (int j = 0; j < SPLIT; ++j) {
            const size_t chunk = (size_t)(b * SPLIT + j);
            den += l_p[chunk * NTOK + n];
            const float4 o = *(const float4*)&Op[(chunk * NTOK + n) * CH + cg * 4];
            acc.x += o.x; acc.y += o.y; acc.z += o.z; acc.w += o.w;
        }
        const float inv = 1.0f / den;
        out[((size_t)b * CH + cg * 4 + 0) * NTOK + n] = acc.x * inv;
        out[((size_t)b * CH + cg * 4 + 1) * NTOK + n] = acc.y * inv;
        out[((size_t)b * CH + cg * 4 + 2) * NTOK + n] = acc.z * inv;
        out[((size_t)b * CH + cg * 4 + 3) * NTOK + n] = acc.w * inv;
    }
}

extern "C" void kernel_launch(void* const* d_in, const int* in_sizes, int n_in,
                              void* d_out, int out_size, void* d_ws, size_t ws_size,
                              hipStream_t stream) {
    const float* x  = (const float*)d_in[0];
    const float* Wq = (const float*)d_in[1];
    const float* bq = (const float*)d_in[2];
    const float* Wk = (const float*)d_in[3];
    const float* bk = (const float*)d_in[4];
    const float* Wv = (const float*)d_in[5];
    const float* bv = (const float*)d_in[6];
    float* out = (float*)d_out;

    const size_t QKV = (size_t)BATCH * NTOK * CH;
    unsigned short* q_ws  = (unsigned short*)d_ws;
    unsigned short* k_ws  = q_ws + QKV;
    unsigned short* vt_ws = k_ws + QKV;
    unsigned short* wb    = vt_ws + QKV;
    float* Op = (float*)(wb + 3 * CH * CH);

    const size_t baseBytes = 3 * QKV * 2 + 3 * CH * CH * 2;
    auto needBytes = [&](size_t S) {
        return baseBytes + S * BATCH * NTOK * (size_t)(CH * 4 + 4);
    };

    convert_w_kernel<<<CH * CH / (256 * 4), 256, 0, stream>>>(Wq, Wk, Wv, wb);

    dim3 gp(NTOK / 64, BATCH);
    proj_mfma_kernel<<<gp, 256, 0, stream>>>(x, wb, wb + CH * CH, wb + 2 * CH * CH,
                                             bq, bk, bv, q_ws, k_ws, vt_ws);

    if (ws_size >= needBytes(8)) {
        float* l_p = Op + (size_t)8 * BATCH * NTOK * CH;
        dim3 ga(NTOK / 128, 8, BATCH);
        flash_attn_mfma<8><<<ga, 256, 0, stream>>>(q_ws, k_ws, vt_ws, out, Op, l_p);
        dim3 gc(NTOK / 32, BATCH);
        combine_kernel<8><<<gc, 256, 0, stream>>>(Op, l_p, out);
    } else if (ws_size >= needBytes(4)) {
        float* l_p = Op + (size_t)4 * BATCH * NTOK * CH;
        dim3 ga(NTOK / 128, 4, BATCH);
        flash_attn_mfma<4><<<ga, 256, 0, stream>>>(q_ws, k_ws, vt_ws, out, Op, l_p);
        dim3 gc(NTOK / 32, BATCH);
        combine_kernel<4><<<gc, 256, 0, stream>>>(Op, l_p, out);
    } else {
        dim3 ga(NTOK / 128, 1, BATCH);
        flash_attn_mfma<1><<<ga, 256, 0, stream>>>(q_ws, k_ws, vt_ws, out,
                                                   nullptr, nullptr);
    }
}

// Round 7
// 179.762 us; speedup vs baseline: 1.3775x; 1.3775x over previous
//
#include <hip/hip_runtime.h>
#include <hip/hip_bf16.h>

// B=4, C=128, H=W=64 -> N=4096. ALL I/O FP32.
// Round 7: flash+combine reverted to Round-5 measured config (58us flash).
// Proj replaced by fat-grid VALU kernel (8192 blocks): proj is only 1.6 GFLOP,
// latency/parallelism was the problem, not arithmetic. convert_w dropped.
// DO NOT tighten __launch_bounds__ on flash: (256,3) forced VGPR 124->84 and
// spilled to scratch (FETCH 35->192 MB, flash 58->150us) in Round 6.

#define BATCH 4
#define CH    128
#define NTOK  4096
#define TK    64
#define SCALE 0.08838834764831845f   // 1/sqrt(128)
#define LOG2E 1.4426950408889634f
#define MFIX  16.0f                  // fixed softmax offset (log2 units)
#define PSTR  72                     // P scratch row stride (ushort)

typedef __attribute__((ext_vector_type(8)))  short short8;
typedef __attribute__((ext_vector_type(16))) float f32x16;

static __device__ __forceinline__ unsigned short f2bf(float f) {
    __hip_bfloat16 h = (__hip_bfloat16)f;
    return *(const unsigned short*)&h;
}

// ---------------- VALU QKV projection (fat grid) ----------------
// grid (NTOK/256, CH, BATCH) = 8192 blocks, 256 thr. Thread: one (b,n,d).
// x coalesced along n; W rows wave-uniform (scalar-cached, L2-hot).
__global__ __launch_bounds__(256) void proj_valu_kernel(
    const float* __restrict__ x,
    const float* __restrict__ Wq, const float* __restrict__ bq,
    const float* __restrict__ Wk, const float* __restrict__ bk,
    const float* __restrict__ Wv, const float* __restrict__ bv,
    unsigned short* __restrict__ q_ws,
    unsigned short* __restrict__ k_ws,
    unsigned short* __restrict__ vt_ws)
{
    const int n = blockIdx.x * blockDim.x + threadIdx.x;
    const int d = blockIdx.y;
    const int b = blockIdx.z;
    const float* xb = x + (size_t)b * CH * NTOK;

    float aq = bq[d];
    float ak = bk[d];
    float av = bv[d];
    #pragma unroll 8
    for (int c = 0; c < CH; ++c) {
        const float xv = xb[(size_t)c * NTOK + n];
        aq = fmaf(Wq[d * CH + c], xv, aq);
        ak = fmaf(Wk[d * CH + c], xv, ak);
        av = fmaf(Wv[d * CH + c], xv, av);
    }
    const size_t o = ((size_t)b * NTOK + n) * CH + d;
    q_ws[o] = f2bf(aq * (SCALE * LOG2E));            // log2-domain scores
    k_ws[o] = f2bf(ak);
    vt_ws[((size_t)b * CH + d) * NTOK + n] = f2bf(av);  // coalesced in n
}

// ---------------- split-KV MFMA flash attention (fixed-m, 32x32 tiles) ------
// block = 256 thr = 4 waves x 32 Q-rows = 128 rows. grid (32, SPLIT, B).
template <int SPLIT>
__global__ __launch_bounds__(256, 2) void flash_attn_mfma(
    const unsigned short* __restrict__ q_ws,
    const unsigned short* __restrict__ k_ws,
    const unsigned short* __restrict__ vt_ws,
    float* __restrict__ out,
    float* __restrict__ Op, float* __restrict__ l_p)
{
    __shared__ __align__(16) unsigned short KsU[TK * CH];        // 16 KB
    __shared__ __align__(16) unsigned short VtU[CH * TK];        // 16 KB
    __shared__ __align__(16) unsigned short PlU[4 * 32 * PSTR];  // 18 KB

    const int t    = threadIdx.x;
    const int w    = t >> 6;
    const int lane = t & 63;
    const int half = lane >> 5;
    const int l32  = lane & 31;
    const int jc   = blockIdx.y;
    const int b    = blockIdx.z;
    const int n0   = blockIdx.x * 128;
    const int jbeg = jc * (NTOK / SPLIT);
    const int jend = jbeg + (NTOK / SPLIT);

    // Q A-frags: wave rows n0+32w .. +31. A[m=l32][k=16ks+8half+j]
    short8 qa[8];
    {
        const unsigned short* qrow = q_ws + ((size_t)b * NTOK + n0 + 32 * w + l32) * CH;
        #pragma unroll
        for (int ks = 0; ks < 8; ++ks)
            qa[ks] = *(const short8*)(qrow + ks * 16 + half * 8);
    }

    f32x16 Oa[4];
    #pragma unroll
    for (int ct = 0; ct < 4; ++ct) Oa[ct] = (f32x16)(0.0f);
    f32x16 La = (f32x16)(0.0f);

    const unsigned short* kg = k_ws  + (size_t)b * NTOK * CH;
    const unsigned short* vg = vt_ws + (size_t)b * CH * NTOK;
    const short8 ones8 = (short8)(short)0x3F80;  // bf16 1.0 x8
    unsigned short* Pw = &PlU[w * 32 * PSTR];

    for (int j0 = jbeg; j0 < jend; j0 += TK) {
        __syncthreads();

        {   // stage K rows 16w..16w+15 (XOR-swizzled source, lane-contig dest)
            const int rl = lane >> 4, u = lane & 15;
            #pragma unroll
            for (int ci = 0; ci < 4; ++ci) {
                const int row = 16 * w + 4 * ci + rl;
                const int g   = u ^ (row & 15);
                const unsigned short* src = kg + (size_t)(j0 + row) * CH + g * 8;
                __builtin_amdgcn_global_load_lds(
                    (const __attribute__((address_space(1))) void*)src,
                    (__attribute__((address_space(3))) void*)&KsU[(16 * w + 4 * ci) * CH],
                    16, 0, 0);
            }
        }
        {   // stage V^T channel rows 32w..32w+31
            const int cl = lane >> 3, u = lane & 7;
            #pragma unroll
            for (int ci = 0; ci < 4; ++ci) {
                const int c = 32 * w + 8 * ci + cl;
                const int g = u ^ (c & 7);
                const unsigned short* src = vg + (size_t)c * NTOK + j0 + g * 8;
                __builtin_amdgcn_global_load_lds(
                    (const __attribute__((address_space(1))) void*)src,
                    (__attribute__((address_space(3))) void*)&VtU[(32 * w + 8 * ci) * TK],
                    16, 0, 0);
            }
        }
        __syncthreads();

        // --- S = Q K^T - MFIX : two 32x32 token tiles, 8 k-steps each ---
        f32x16 s0 = (f32x16)(-MFIX);
        f32x16 s1 = (f32x16)(-MFIX);
        #pragma unroll
        for (int ks = 0; ks < 8; ++ks) {
            const int ph = (2 * ks + half) ^ (l32 & 15);
            const short8 kf0 = *(const short8*)&KsU[l32 * CH + ph * 8];
            const short8 kf1 = *(const short8*)&KsU[(32 + l32) * CH + ph * 8];
            s0 = __builtin_amdgcn_mfma_f32_32x32x16_bf16(qa[ks], kf0, s0, 0, 0, 0);
            s1 = __builtin_amdgcn_mfma_f32_32x32x16_bf16(qa[ks], kf1, s1, 0, 0, 0);
        }

        // --- P = exp2(S) (m fixed) -> per-wave LDS scratch, row-major ---
        #pragma unroll
        for (int reg = 0; reg < 16; ++reg) {
            const int row = (reg & 3) + 8 * (reg >> 2) + 4 * half;
            Pw[row * PSTR + l32]      = f2bf(exp2f(s0[reg]));
            Pw[row * PSTR + 32 + l32] = f2bf(exp2f(s1[reg]));
        }
        __threadfence_block();

        // --- O += P V ; l += P * ones (no rescale: m is fixed) ---
        #pragma unroll
        for (int ks2 = 0; ks2 < 4; ++ks2) {
            const short8 pa = *(const short8*)&Pw[l32 * PSTR + ks2 * 16 + half * 8];
            #pragma unroll
            for (int ct = 0; ct < 4; ++ct) {
                const int ch = ct * 32 + l32;
                const int ph = (2 * ks2 + half) ^ (ch & 7);
                const short8 vf = *(const short8*)&VtU[ch * TK + ph * 8];
                Oa[ct] = __builtin_amdgcn_mfma_f32_32x32x16_bf16(pa, vf, Oa[ct], 0, 0, 0);
            }
            La = __builtin_amdgcn_mfma_f32_32x32x16_bf16(pa, ones8, La, 0, 0, 0);
        }
    }

    if constexpr (SPLIT == 1) {
        #pragma unroll
        for (int reg = 0; reg < 16; ++reg) {
            const int row = (reg & 3) + 8 * (reg >> 2) + 4 * half;
            const int n = n0 + 32 * w + row;
            const float inv = 1.0f / La[reg];
            #pragma unroll
            for (int ct = 0; ct < 4; ++ct)
                out[((size_t)b * CH + ct * 32 + l32) * NTOK + n] = Oa[ct][reg] * inv;
        }
    } else {
        const size_t chunk = (size_t)(b * SPLIT + jc);
        #pragma unroll
        for (int reg = 0; reg < 16; ++reg) {
            const int row = (reg & 3) + 8 * (reg >> 2) + 4 * half;
            const int n = n0 + 32 * w + row;
            const size_t base = (chunk * NTOK + n) * CH;
            #pragma unroll
            for (int ct = 0; ct < 4; ++ct)
                Op[base + ct * 32 + l32] = Oa[ct][reg];
            if (l32 == 0) l_p[chunk * NTOK + n] = La[reg];
        }
    }
}

// ---------------- combine partials (plain sums; fixed m) ----------------
template <int SPLIT>
__global__ __launch_bounds__(256) void combine_kernel(
    const float* __restrict__ Op, const float* __restrict__ l_p,
    float* __restrict__ out)
{
    const int t  = threadIdx.x;
    const int cg = t & 31;
    const int r8 = t >> 5;
    const int n0 = blockIdx.x * 32;
    const int b  = blockIdx.y;

    for (int it = 0; it < 4; ++it) {
        const int n = n0 + it * 8 + r8;
        float den = 0.f;
        float4 acc = make_float4(0.f, 0.f, 0.f, 0.f);
        #pragma unroll
        for (int j = 0; j < SPLIT; ++j) {
            const size_t chunk = (size_t)(b * SPLIT + j);
            den += l_p[chunk * NTOK + n];
            const float4 o = *(const float4*)&Op[(chunk * NTOK + n) * CH + cg * 4];
            acc.x += o.x; acc.y += o.y; acc.z += o.z; acc.w += o.w;
        }
        const float inv = 1.0f / den;
        out[((size_t)b * CH + cg * 4 + 0) * NTOK + n] = acc.x * inv;
        out[((size_t)b * CH + cg * 4 + 1) * NTOK + n] = acc.y * inv;
        out[((size_t)b * CH + cg * 4 + 2) * NTOK + n] = acc.z * inv;
        out[((size_t)b * CH + cg * 4 + 3) * NTOK + n] = acc.w * inv;
    }
}

extern "C" void kernel_launch(void* const* d_in, const int* in_sizes, int n_in,
                              void* d_out, int out_size, void* d_ws, size_t ws_size,
                              hipStream_t stream) {
    const float* x  = (const float*)d_in[0];
    const float* Wq = (const float*)d_in[1];
    const float* bq = (const float*)d_in[2];
    const float* Wk = (const float*)d_in[3];
    const float* bk = (const float*)d_in[4];
    const float* Wv = (const float*)d_in[5];
    const float* bv = (const float*)d_in[6];
    float* out = (float*)d_out;

    const size_t QKV = (size_t)BATCH * NTOK * CH;
    unsigned short* q_ws  = (unsigned short*)d_ws;
    unsigned short* k_ws  = q_ws + QKV;
    unsigned short* vt_ws = k_ws + QKV;
    float* Op = (float*)(vt_ws + QKV);

    const size_t baseBytes = 3 * QKV * 2;
    auto needBytes = [&](size_t S) {
        return baseBytes + S * BATCH * NTOK * (size_t)(CH * 4 + 4);
    };

    dim3 gp(NTOK / 256, CH, BATCH);
    proj_valu_kernel<<<gp, 256, 0, stream>>>(x, Wq, bq, Wk, bk, Wv, bv,
                                             q_ws, k_ws, vt_ws);

    if (ws_size >= needBytes(8)) {
        float* l_p = Op + (size_t)8 * BATCH * NTOK * CH;
        dim3 ga(NTOK / 128, 8, BATCH);
        flash_attn_mfma<8><<<ga, 256, 0, stream>>>(q_ws, k_ws, vt_ws, out, Op, l_p);
        dim3 gc(NTOK / 32, BATCH);
        combine_kernel<8><<<gc, 256, 0, stream>>>(Op, l_p, out);
    } else if (ws_size >= needBytes(4)) {
        float* l_p = Op + (size_t)4 * BATCH * NTOK * CH;
        dim3 ga(NTOK / 128, 4, BATCH);
        flash_attn_mfma<4><<<ga, 256, 0, stream>>>(q_ws, k_ws, vt_ws, out, Op, l_p);
        dim3 gc(NTOK / 32, BATCH);
        combine_kernel<4><<<gc, 256, 0, stream>>>(Op, l_p, out);
    } else {
        dim3 ga(NTOK / 128, 1, BATCH);
        flash_attn_mfma<1><<<ga, 256, 0, stream>>>(q_ws, k_ws, vt_ws, out,
                                                   nullptr, nullptr);
    }
}